// Round 21
// baseline (146.669 us; speedup 1.0000x reference)
//
#include <hip/hip_runtime.h>
#include <stdint.h>

typedef __bf16 bf16;
typedef __bf16 bf16x8 __attribute__((ext_vector_type(8)));
typedef float f32x4 __attribute__((ext_vector_type(4)));

__device__ __forceinline__ void gload_lds16(const void* g, void* l) {
    __builtin_amdgcn_global_load_lds((const __attribute__((address_space(1))) void*)g,
                                     (__attribute__((address_space(3))) void*)l, 16, 0, 0);
}

__device__ __forceinline__ float fast_exp2(float x) { return __builtin_amdgcn_exp2f(x); }

// ---------------- K0: fused prep: cast x, transpose weights, mask scan ----------------
__global__ __launch_bounds__(256) void k_prep(const float* __restrict__ x, bf16* __restrict__ xb,
                                              const float* __restrict__ Wqkv, bf16* __restrict__ WqT,
                                              const float* __restrict__ Wout, bf16* __restrict__ WoT,
                                              const int* __restrict__ mask, int* __restrict__ idxU,
                                              int* __restrict__ cpos, int* __restrict__ meta) {
    __shared__ float t[32][33];
    __shared__ int lsum[256];
    int b = blockIdx.x, tid = threadIdx.x;
    if (b < 4096) {
        int i = b * 256 + tid;
        const f32x4* p = (const f32x4*)(x + (size_t)i * 8);
        f32x4 a = p[0], c = p[1];
        bf16x8 o;
        o[0] = (bf16)a[0]; o[1] = (bf16)a[1]; o[2] = (bf16)a[2]; o[3] = (bf16)a[3];
        o[4] = (bf16)c[0]; o[5] = (bf16)c[1]; o[6] = (bf16)c[2]; o[7] = (bf16)c[3];
        *(bf16x8*)(xb + (size_t)i * 8) = o;
    } else if (b < 4096 + 768 + 256) {
        const float* W; bf16* WT; int C, bb;
        if (b < 4096 + 768) { W = Wqkv; WT = WqT; C = 1536; bb = b - 4096; }
        else                { W = Wout; WT = WoT; C = 512;  bb = b - 4864; }
        int nblk = C / 32;
        int n0 = (bb % nblk) * 32, k0 = (bb / nblk) * 32;
        int tx = tid & 31, ty = tid >> 5;
        for (int i = 0; i < 32; i += 8) t[ty + i][tx] = W[(size_t)(k0 + ty + i) * C + n0 + tx];
        __syncthreads();
        for (int i = 0; i < 32; i += 8) WT[(size_t)(n0 + ty + i) * 512 + k0 + tx] = (bf16)t[tx][ty + i];
    } else {
        int m[4], s = 0;
#pragma unroll
        for (int e = 0; e < 4; e++) { m[e] = mask[4 * tid + e]; s += m[e]; }
        lsum[tid] = s;
        __syncthreads();
        for (int off = 1; off < 256; off <<= 1) {
            int v = (tid >= off) ? lsum[tid - off] : 0;
            __syncthreads();
            lsum[tid] += v;
            __syncthreads();
        }
        int run = lsum[tid] - s;
#pragma unroll
        for (int e = 0; e < 4; e++) {
            if (m[e]) { idxU[run] = 4 * tid + e; cpos[4 * tid + e] = run; run++; }
            else cpos[4 * tid + e] = -1;
        }
        int nU = lsum[255];
        for (int i = nU + tid; i < 1024; i += 256) idxU[i] = 0;   // pad rows -> row 0 (masked later)
        if (tid == 255) { meta[0] = nU; meta[1] = (nU + 63) >> 6; }
    }
}

// ---------------- K1: qkv GEMM 128x128, BK=32 double-buffered (R14-proven) ----------------
__global__ __launch_bounds__(256, 4) void k_qkv(const bf16* __restrict__ Xb, const bf16* __restrict__ WT,
                                                bf16* __restrict__ Qb, bf16* __restrict__ Kb, bf16* __restrict__ Vb) {
    __shared__ char As[2][8192], Bs[2][8192];
    int tid = threadIdx.x, l = tid & 63, w = tid >> 6;
    int wy = w >> 1, wx = w & 1;
    int id = blockIdx.x;
    int wg = (id & 7) * 192 + (id >> 3);          // 1536 = 8*192, bijective XCD chunking
    int bm = (wg / 12) * 128, bn = (wg % 12) * 128;
    int lr = l & 15, kg = l >> 4;

    int subr = l >> 2, chk = l & 3;
    int R0 = w * 32 + subr,      m0 = (R0 >> 1) & 3, c0 = chk ^ m0;
    int R1 = w * 32 + 16 + subr, m1 = (R1 >> 1) & 3, c1 = chk ^ m1;

    f32x4 acc[4][4] = {};

    gload_lds16((const char*)Xb + ((size_t)(bm + R0) * 512) * 2 + c0 * 16, As[0] + w * 2048 + l * 16);
    gload_lds16((const char*)Xb + ((size_t)(bm + R1) * 512) * 2 + c1 * 16, As[0] + w * 2048 + 1024 + l * 16);
    gload_lds16((const char*)WT + ((size_t)(bn + R0) * 512) * 2 + c0 * 16, Bs[0] + w * 2048 + l * 16);
    gload_lds16((const char*)WT + ((size_t)(bn + R1) * 512) * 2 + c1 * 16, Bs[0] + w * 2048 + 1024 + l * 16);
    __syncthreads();

    for (int t = 0; t < 16; t++) {
        int cur = t & 1;
        if (t < 15) {
            int k1 = (t + 1) * 32;
            gload_lds16((const char*)Xb + ((size_t)(bm + R0) * 512 + k1) * 2 + c0 * 16, As[cur ^ 1] + w * 2048 + l * 16);
            gload_lds16((const char*)Xb + ((size_t)(bm + R1) * 512 + k1) * 2 + c1 * 16, As[cur ^ 1] + w * 2048 + 1024 + l * 16);
            gload_lds16((const char*)WT + ((size_t)(bn + R0) * 512 + k1) * 2 + c0 * 16, Bs[cur ^ 1] + w * 2048 + l * 16);
            gload_lds16((const char*)WT + ((size_t)(bn + R1) * 512 + k1) * 2 + c1 * 16, Bs[cur ^ 1] + w * 2048 + 1024 + l * 16);
        }

        bf16x8 af[4], bfr[4];
#pragma unroll
        for (int mt = 0; mt < 4; mt++) {
            int r = wy * 64 + mt * 16 + lr;
            af[mt] = *(const bf16x8*)(As[cur] + r * 64 + ((kg ^ ((r >> 1) & 3)) << 4));
        }
#pragma unroll
        for (int nt = 0; nt < 4; nt++) {
            int r = wx * 64 + nt * 16 + lr;
            bfr[nt] = *(const bf16x8*)(Bs[cur] + r * 64 + ((kg ^ ((r >> 1) & 3)) << 4));
        }
#pragma unroll
        for (int mt = 0; mt < 4; mt++)
#pragma unroll
            for (int nt = 0; nt < 4; nt++)
                acc[mt][nt] = __builtin_amdgcn_mfma_f32_16x16x32_bf16(af[mt], bfr[nt], acc[mt][nt], 0, 0, 0);

        __syncthreads();
    }

#pragma unroll
    for (int mt = 0; mt < 4; mt++) {
#pragma unroll
        for (int nt = 0; nt < 4; nt++) {
            int c = bn + wx * 64 + nt * 16 + lr;
            int which = c >> 9, hd = c & 511, h = hd >> 6, d = hd & 63;
            float qs = (which == 0) ? 0.18033688f : 1.0f;   // 0.125 * log2(e)
            bf16* base = (which == 0) ? Qb : (which == 1) ? Kb : Vb;
#pragma unroll
            for (int j = 0; j < 4; j++) {
                int m = bm + wy * 64 + mt * 16 + kg * 4 + j;
                int f = m >> 10, nn = m & 1023;
                base[((size_t)(h * 16 + f) * 1024 + nn) * 64 + d] = (bf16)(acc[mt][nt][j] * qs);
            }
        }
    }
}

// ---------------- K1c: gather+transpose V -> Vtc [b'][d][c], zero-pad ----------------
__global__ __launch_bounds__(256) void k_vtg(const bf16* __restrict__ V, bf16* __restrict__ Vtc,
                                             const int* __restrict__ idxU, const int* __restrict__ meta) {
    __shared__ bf16 t[64][80];
    int bp = blockIdx.y, c0 = blockIdx.x * 64;
    int nU = meta[0], nUp = meta[1] << 6;
    if (c0 >= nUp) return;
    int tid = threadIdx.x;
    int nl = tid >> 2, dc = (tid & 3) * 16;
    int c = c0 + nl;
    bf16x8 a0 = {}, a1 = {};
    if (c < nU) {
        int row = idxU[c];
        const bf16* src = V + ((size_t)bp * 1024 + row) * 64 + dc;
        a0 = *(const bf16x8*)src;
        a1 = *(const bf16x8*)(src + 8);
    }
    *(bf16x8*)&t[nl][dc] = a0;
    *(bf16x8*)&t[nl][dc + 8] = a1;
    __syncthreads();
    int dl = tid >> 2, nc = (tid & 3) * 16;
    bf16x8 o0, o1;
#pragma unroll
    for (int i = 0; i < 8; i++) o0[i] = t[nc + i][dl];
#pragma unroll
    for (int i = 0; i < 8; i++) o1[i] = t[nc + 8 + i][dl];
    bf16* dst = Vtc + ((size_t)bp * 64 + dl) * 1024 + c0 + nc;
    *(bf16x8*)dst = o0;
    *(bf16x8*)(dst + 8) = o1;
}

// ---------------- K2: flash attention, T14 async-STAGE split (reg-staged K/V) ----------
__global__ __launch_bounds__(512, 6) void k_attn(const bf16* __restrict__ Qb, const bf16* __restrict__ Kb,
                                                 const bf16* __restrict__ Vtc, bf16* __restrict__ AO,
                                                 const int* __restrict__ cpos, const int* __restrict__ idxU,
                                                 const int* __restrict__ meta, const int* __restrict__ diagp) {
    __shared__ char Ks[8192], Vs[8192], Ps[16384];
    int tid = threadIdx.x, l = tid & 63, w = tid >> 6;   // w: 0..7
    int id = blockIdx.x;
    int wg = (id & 7) * 128 + (id >> 3);          // 1024 = 8*128: 16 whole bp's per XCD
    int qt = wg & 7, bp = wg >> 3;                // 8 q-tiles of 128 rows
    int lr = l & 15, kg = l >> 4;
    int diag = diagp[0];
    int nU = meta[0], nT = meta[1];

    int nq = qt * 128 + w * 16 + lr;
    const char* Qrow = (const char*)Qb + ((size_t)bp * 1024 + nq) * 128;
    bf16x8 qf0 = *(const bf16x8*)(Qrow + kg * 16);
    bf16x8 qf1 = *(const bf16x8*)(Qrow + 64 + kg * 16);

    int cq[4];
#pragma unroll
    for (int j = 0; j < 4; j++) {
        int qg = qt * 128 + w * 16 + kg * 4 + j;
        cq[j] = diag ? cpos[qg] : -1;
    }
    int cqmax = cq[0];
#pragma unroll
    for (int j = 1; j < 4; j++) cqmax = (cq[j] > cqmax) ? cq[j] : cqmax;
    int cqmin = cq[0];
#pragma unroll
    for (int j = 1; j < 4; j++) cqmin = (cq[j] < cqmin) ? cq[j] : cqmin;
    int dtile_lo = cqmin >> 6, dtile_hi = cqmax >> 6;

    const char* Kbb = (const char*)Kb + (size_t)bp * 1024 * 128;
    const char* Vbase = (const char*)Vtc + (size_t)bp * 64 * 2048;

    int rs = tid >> 3;                            // staging row 0..63
    int cs = (tid & 7) ^ (rs & 7);                // pre-swizzled source chunk

    f32x4 o[4] = {};
    f32x4 psum = {0.f, 0.f, 0.f, 0.f};

    bf16x8 kreg = *(const bf16x8*)(Kbb + (size_t)idxU[rs] * 128 + cs * 16);
    bf16x8 vreg = *(const bf16x8*)(Vbase + (size_t)rs * 2048 + cs * 16);

    for (int kt = 0; kt < nT; kt++) {
        __syncthreads();   // all reads of tile kt-1 done
        *(bf16x8*)(Ks + tid * 16) = kreg;
        *(bf16x8*)(Vs + tid * 16) = vreg;
        if (kt + 1 < nT) {
            kreg = *(const bf16x8*)(Kbb + (size_t)idxU[(kt + 1) * 64 + rs] * 128 + cs * 16);
            vreg = *(const bf16x8*)(Vbase + (size_t)rs * 2048 + (kt + 1) * 128 + cs * 16);
        }
        __syncthreads();   // ds_writes visible

        f32x4 s[4] = {};
        __builtin_amdgcn_s_setprio(1);
#pragma unroll
        for (int nt = 0; nt < 4; nt++) {
            int r = nt * 16 + lr;
            bf16x8 kf0 = *(const bf16x8*)(Ks + r * 128 + ((kg ^ (r & 7)) << 4));
            bf16x8 kf1 = *(const bf16x8*)(Ks + r * 128 + (((4 + kg) ^ (r & 7)) << 4));
            s[nt] = __builtin_amdgcn_mfma_f32_16x16x32_bf16(qf0, kf0, s[nt], 0, 0, 0);
            s[nt] = __builtin_amdgcn_mfma_f32_16x16x32_bf16(qf1, kf1, s[nt], 0, 0, 0);
        }
        __builtin_amdgcn_s_setprio(0);

#pragma unroll
        for (int nt = 0; nt < 4; nt++)
#pragma unroll
            for (int j = 0; j < 4; j++) s[nt][j] = fast_exp2(s[nt][j]);

        if (kt == nT - 1) {
            float mf0 = (kt * 64 + lr < nU) ? 1.f : 0.f;
            float mf1 = (kt * 64 + 16 + lr < nU) ? 1.f : 0.f;
            float mf2 = (kt * 64 + 32 + lr < nU) ? 1.f : 0.f;
            float mf3 = (kt * 64 + 48 + lr < nU) ? 1.f : 0.f;
#pragma unroll
            for (int j = 0; j < 4; j++) {
                s[0][j] *= mf0; s[1][j] *= mf1; s[2][j] *= mf2; s[3][j] *= mf3;
            }
        }
        if (kt >= dtile_lo && kt <= dtile_hi) {
#pragma unroll
            for (int nt = 0; nt < 4; nt++) {
                int c = kt * 64 + nt * 16 + lr;
#pragma unroll
                for (int j = 0; j < 4; j++)
                    if (c == cq[j]) s[nt][j] = 0.f;
            }
        }
#pragma unroll
        for (int j = 0; j < 4; j++) psum[j] += (s[0][j] + s[1][j]) + (s[2][j] + s[3][j]);

#pragma unroll
        for (int nt = 0; nt < 4; nt++)
#pragma unroll
            for (int j = 0; j < 4; j++) {
                int rq = w * 16 + kg * 4 + j;
                int byte = (rq * 128 + (nt * 16 + lr) * 2) ^ ((rq & 7) << 4);
                *(bf16*)(Ps + byte) = (bf16)s[nt][j];
            }

        int rp = w * 16 + lr;
        bf16x8 pf0 = *(const bf16x8*)(Ps + rp * 128 + ((kg ^ (rp & 7)) << 4));
        bf16x8 pf1 = *(const bf16x8*)(Ps + rp * 128 + (((4 + kg) ^ (rp & 7)) << 4));
        __builtin_amdgcn_s_setprio(1);
#pragma unroll
        for (int dt = 0; dt < 4; dt++) {
            int rd = dt * 16 + lr;
            bf16x8 vf0 = *(const bf16x8*)(Vs + rd * 128 + ((kg ^ (rd & 7)) << 4));
            bf16x8 vf1 = *(const bf16x8*)(Vs + rd * 128 + (((4 + kg) ^ (rd & 7)) << 4));
            o[dt] = __builtin_amdgcn_mfma_f32_16x16x32_bf16(pf0, vf0, o[dt], 0, 0, 0);
            o[dt] = __builtin_amdgcn_mfma_f32_16x16x32_bf16(pf1, vf1, o[dt], 0, 0, 0);
        }
        __builtin_amdgcn_s_setprio(0);
    }

#pragma unroll
    for (int off = 1; off < 16; off <<= 1)
#pragma unroll
        for (int j = 0; j < 4; j++) psum[j] += __shfl_xor(psum[j], off, 64);
    float inv[4];
#pragma unroll
    for (int j = 0; j < 4; j++) inv[j] = 1.0f / psum[j];

    int f = bp & 15, h = bp >> 4;
#pragma unroll
    for (int dt = 0; dt < 4; dt++)
#pragma unroll
        for (int j = 0; j < 4; j++) {
            int n = qt * 128 + w * 16 + kg * 4 + j;
            size_t m = (size_t)f * 1024 + n;
            AO[m * 512 + h * 64 + dt * 16 + lr] = (bf16)(o[dt][j] * inv[j]);
        }
}

// ---------------- K3: out = AO @ WoutT^T (fp32 out), BK=32 double-buffered ----------------
__global__ __launch_bounds__(256, 4) void k_out(const bf16* __restrict__ Ab, const bf16* __restrict__ WT,
                                                float* __restrict__ out) {
    __shared__ char As[2][8192], Bs[2][8192];
    int tid = threadIdx.x, l = tid & 63, w = tid >> 6;
    int wy = w >> 1, wx = w & 1;
    int id = blockIdx.x;
    int wg = (id & 7) * 64 + (id >> 3);           // 512 = 8*64
    int bm = (wg / 4) * 128, bn = (wg % 4) * 128;
    int lr = l & 15, kg = l >> 4;

    int subr = l >> 2, chk = l & 3;
    int R0 = w * 32 + subr,      m0 = (R0 >> 1) & 3, c0 = chk ^ m0;
    int R1 = w * 32 + 16 + subr, m1 = (R1 >> 1) & 3, c1 = chk ^ m1;

    f32x4 acc[4][4] = {};

    gload_lds16((const char*)Ab + ((size_t)(bm + R0) * 512) * 2 + c0 * 16, As[0] + w * 2048 + l * 16);
    gload_lds16((const char*)Ab + ((size_t)(bm + R1) * 512) * 2 + c1 * 16, As[0] + w * 2048 + 1024 + l * 16);
    gload_lds16((const char*)WT + ((size_t)(bn + R0) * 512) * 2 + c0 * 16, Bs[0] + w * 2048 + l * 16);
    gload_lds16((const char*)WT + ((size_t)(bn + R1) * 512) * 2 + c1 * 16, Bs[0] + w * 2048 + 1024 + l * 16);
    __syncthreads();

    for (int t = 0; t < 16; t++) {
        int cur = t & 1;
        if (t < 15) {
            int k1 = (t + 1) * 32;
            gload_lds16((const char*)Ab + ((size_t)(bm + R0) * 512 + k1) * 2 + c0 * 16, As[cur ^ 1] + w * 2048 + l * 16);
            gload_lds16((const char*)Ab + ((size_t)(bm + R1) * 512 + k1) * 2 + c1 * 16, As[cur ^ 1] + w * 2048 + 1024 + l * 16);
            gload_lds16((const char*)WT + ((size_t)(bn + R0) * 512 + k1) * 2 + c0 * 16, Bs[cur ^ 1] + w * 2048 + l * 16);
            gload_lds16((const char*)WT + ((size_t)(bn + R1) * 512 + k1) * 2 + c1 * 16, Bs[cur ^ 1] + w * 2048 + 1024 + l * 16);
        }

        bf16x8 af[4], bfr[4];
#pragma unroll
        for (int mt = 0; mt < 4; mt++) {
            int r = wy * 64 + mt * 16 + lr;
            af[mt] = *(const bf16x8*)(As[cur] + r * 64 + ((kg ^ ((r >> 1) & 3)) << 4));
        }
#pragma unroll
        for (int nt = 0; nt < 4; nt++) {
            int r = wx * 64 + nt * 16 + lr;
            bfr[nt] = *(const bf16x8*)(Bs[cur] + r * 64 + ((kg ^ ((r >> 1) & 3)) << 4));
        }
#pragma unroll
        for (int mt = 0; mt < 4; mt++)
#pragma unroll
            for (int nt = 0; nt < 4; nt++)
                acc[mt][nt] = __builtin_amdgcn_mfma_f32_16x16x32_bf16(af[mt], bfr[nt], acc[mt][nt], 0, 0, 0);

        __syncthreads();
    }

#pragma unroll
    for (int mt = 0; mt < 4; mt++)
#pragma unroll
        for (int nt = 0; nt < 4; nt++) {
            int c = bn + wx * 64 + nt * 16 + lr;
#pragma unroll
            for (int j = 0; j < 4; j++) {
                int m = bm + wy * 64 + mt * 16 + kg * 4 + j;
                out[(size_t)m * 512 + c] = acc[mt][nt][j];
            }
        }
}

extern "C" void kernel_launch(void* const* d_in, const int* in_sizes, int n_in,
                              void* d_out, int out_size, void* d_ws, size_t ws_size,
                              hipStream_t stream) {
    const float* x    = (const float*)d_in[0];
    const float* Wqkv = (const float*)d_in[1];
    const float* Wout = (const float*)d_in[2];
    const int*   mask = (const int*)d_in[3];
    const int*   diag = (const int*)d_in[4];
    float* out = (float*)d_out;
    char* ws = (char*)d_ws;

    bf16* Xb  = (bf16*)(ws);                             // 16 MB, dead after k_qkv
    bf16* Vtc = (bf16*)(ws);                             // V^T compacted, reuses Xb
    bf16* WqT = (bf16*)(ws + ((size_t)16 << 20));        // 1.5 MB
    bf16* WoT = (bf16*)(ws + ((size_t)18 << 20));        // 0.5 MB
    int*  idxU = (int*)(ws + ((size_t)18 << 20) + (1 << 19));            // 4 KB
    int*  cpos = (int*)(ws + ((size_t)18 << 20) + (1 << 19) + 4096);     // 4 KB
    int*  meta = (int*)(ws + ((size_t)18 << 20) + (1 << 19) + 8192);     // 8 B
    bf16* Qb  = (bf16*)(ws + ((size_t)19 << 20));        // 16 MB
    bf16* Kb  = (bf16*)(ws + ((size_t)35 << 20));        // 16 MB (row-major K, live through k_attn)
    bf16* Vb  = (bf16*)(ws + ((size_t)51 << 20));        // 16 MB, dead after k_vtg
    bf16* AO  = (bf16*)(ws + ((size_t)67 << 20));        // 16 MB

    hipLaunchKernelGGL(k_prep, dim3(4096 + 768 + 256 + 1), dim3(256), 0, stream,
                       x, Xb, Wqkv, WqT, Wout, WoT, mask, idxU, cpos, meta);
    hipLaunchKernelGGL(k_qkv, dim3(1536), dim3(256), 0, stream, Xb, WqT, Qb, Kb, Vb);
    hipLaunchKernelGGL(k_vtg, dim3(16, 128), dim3(256), 0, stream, Vb, Vtc, idxU, meta);
    hipLaunchKernelGGL(k_attn, dim3(1024), dim3(512), 0, stream, Qb, Kb, Vtc, AO, cpos, idxU, meta, diag);
    hipLaunchKernelGGL(k_out, dim3(512), dim3(256), 0, stream, AO, WoT, out);
}

// Round 22
// 108.771 us; speedup vs baseline: 1.3484x; 1.3484x over previous
//
#include <hip/hip_runtime.h>
#include <stdint.h>

typedef __bf16 bf16;
typedef __bf16 bf16x8 __attribute__((ext_vector_type(8)));
typedef float f32x4 __attribute__((ext_vector_type(4)));

__device__ __forceinline__ void gload_lds16(const void* g, void* l) {
    __builtin_amdgcn_global_load_lds((const __attribute__((address_space(1))) void*)g,
                                     (__attribute__((address_space(3))) void*)l, 16, 0, 0);
}

__device__ __forceinline__ float fast_exp2(float x) { return __builtin_amdgcn_exp2f(x); }

// ---------------- K0: fused prep: cast x, transpose weights, mask scan ----------------
__global__ __launch_bounds__(256) void k_prep(const float* __restrict__ x, bf16* __restrict__ xb,
                                              const float* __restrict__ Wqkv, bf16* __restrict__ WqT,
                                              const float* __restrict__ Wout, bf16* __restrict__ WoT,
                                              const int* __restrict__ mask, int* __restrict__ idxU,
                                              int* __restrict__ cpos, int* __restrict__ meta) {
    __shared__ float t[32][33];
    __shared__ int lsum[256];
    int b = blockIdx.x, tid = threadIdx.x;
    if (b < 4096) {
        int i = b * 256 + tid;
        const f32x4* p = (const f32x4*)(x + (size_t)i * 8);
        f32x4 a = p[0], c = p[1];
        bf16x8 o;
        o[0] = (bf16)a[0]; o[1] = (bf16)a[1]; o[2] = (bf16)a[2]; o[3] = (bf16)a[3];
        o[4] = (bf16)c[0]; o[5] = (bf16)c[1]; o[6] = (bf16)c[2]; o[7] = (bf16)c[3];
        *(bf16x8*)(xb + (size_t)i * 8) = o;
    } else if (b < 4096 + 768 + 256) {
        const float* W; bf16* WT; int C, bb;
        if (b < 4096 + 768) { W = Wqkv; WT = WqT; C = 1536; bb = b - 4096; }
        else                { W = Wout; WT = WoT; C = 512;  bb = b - 4864; }
        int nblk = C / 32;
        int n0 = (bb % nblk) * 32, k0 = (bb / nblk) * 32;
        int tx = tid & 31, ty = tid >> 5;
        for (int i = 0; i < 32; i += 8) t[ty + i][tx] = W[(size_t)(k0 + ty + i) * C + n0 + tx];
        __syncthreads();
        for (int i = 0; i < 32; i += 8) WT[(size_t)(n0 + ty + i) * 512 + k0 + tx] = (bf16)t[tx][ty + i];
    } else {
        int m[4], s = 0;
#pragma unroll
        for (int e = 0; e < 4; e++) { m[e] = mask[4 * tid + e]; s += m[e]; }
        lsum[tid] = s;
        __syncthreads();
        for (int off = 1; off < 256; off <<= 1) {
            int v = (tid >= off) ? lsum[tid - off] : 0;
            __syncthreads();
            lsum[tid] += v;
            __syncthreads();
        }
        int run = lsum[tid] - s;
#pragma unroll
        for (int e = 0; e < 4; e++) {
            if (m[e]) { idxU[run] = 4 * tid + e; cpos[4 * tid + e] = run; run++; }
            else cpos[4 * tid + e] = -1;
        }
        int nU = lsum[255];
        for (int i = nU + tid; i < 1024; i += 256) idxU[i] = 0;   // pad rows -> row 0 (masked later)
        if (tid == 255) { meta[0] = nU; meta[1] = (nU + 63) >> 6; }
    }
}

// ---------------- K1: qkv GEMM 128x128, BK=32 double-buffered (R14-proven) ----------------
__global__ __launch_bounds__(256) void k_qkv(const bf16* __restrict__ Xb, const bf16* __restrict__ WT,
                                             bf16* __restrict__ Qb, bf16* __restrict__ Kb, bf16* __restrict__ Vb) {
    __shared__ char As[2][8192], Bs[2][8192];
    int tid = threadIdx.x, l = tid & 63, w = tid >> 6;
    int wy = w >> 1, wx = w & 1;
    int id = blockIdx.x;
    int wg = (id & 7) * 192 + (id >> 3);          // 1536 = 8*192, bijective XCD chunking
    int bm = (wg / 12) * 128, bn = (wg % 12) * 128;
    int lr = l & 15, kg = l >> 4;

    int subr = l >> 2, chk = l & 3;
    int R0 = w * 32 + subr,      m0 = (R0 >> 1) & 3, c0 = chk ^ m0;
    int R1 = w * 32 + 16 + subr, m1 = (R1 >> 1) & 3, c1 = chk ^ m1;

    f32x4 acc[4][4] = {};

    gload_lds16((const char*)Xb + ((size_t)(bm + R0) * 512) * 2 + c0 * 16, As[0] + w * 2048 + l * 16);
    gload_lds16((const char*)Xb + ((size_t)(bm + R1) * 512) * 2 + c1 * 16, As[0] + w * 2048 + 1024 + l * 16);
    gload_lds16((const char*)WT + ((size_t)(bn + R0) * 512) * 2 + c0 * 16, Bs[0] + w * 2048 + l * 16);
    gload_lds16((const char*)WT + ((size_t)(bn + R1) * 512) * 2 + c1 * 16, Bs[0] + w * 2048 + 1024 + l * 16);
    __syncthreads();

    for (int t = 0; t < 16; t++) {
        int cur = t & 1;
        if (t < 15) {
            int k1 = (t + 1) * 32;
            gload_lds16((const char*)Xb + ((size_t)(bm + R0) * 512 + k1) * 2 + c0 * 16, As[cur ^ 1] + w * 2048 + l * 16);
            gload_lds16((const char*)Xb + ((size_t)(bm + R1) * 512 + k1) * 2 + c1 * 16, As[cur ^ 1] + w * 2048 + 1024 + l * 16);
            gload_lds16((const char*)WT + ((size_t)(bn + R0) * 512 + k1) * 2 + c0 * 16, Bs[cur ^ 1] + w * 2048 + l * 16);
            gload_lds16((const char*)WT + ((size_t)(bn + R1) * 512 + k1) * 2 + c1 * 16, Bs[cur ^ 1] + w * 2048 + 1024 + l * 16);
        }

        bf16x8 af[4], bfr[4];
#pragma unroll
        for (int mt = 0; mt < 4; mt++) {
            int r = wy * 64 + mt * 16 + lr;
            af[mt] = *(const bf16x8*)(As[cur] + r * 64 + ((kg ^ ((r >> 1) & 3)) << 4));
        }
#pragma unroll
        for (int nt = 0; nt < 4; nt++) {
            int r = wx * 64 + nt * 16 + lr;
            bfr[nt] = *(const bf16x8*)(Bs[cur] + r * 64 + ((kg ^ ((r >> 1) & 3)) << 4));
        }
#pragma unroll
        for (int mt = 0; mt < 4; mt++)
#pragma unroll
            for (int nt = 0; nt < 4; nt++)
                acc[mt][nt] = __builtin_amdgcn_mfma_f32_16x16x32_bf16(af[mt], bfr[nt], acc[mt][nt], 0, 0, 0);

        __syncthreads();
    }

#pragma unroll
    for (int mt = 0; mt < 4; mt++) {
#pragma unroll
        for (int nt = 0; nt < 4; nt++) {
            int c = bn + wx * 64 + nt * 16 + lr;
            int which = c >> 9, hd = c & 511, h = hd >> 6, d = hd & 63;
            float qs = (which == 0) ? 0.18033688f : 1.0f;   // 0.125 * log2(e)
            bf16* base = (which == 0) ? Qb : (which == 1) ? Kb : Vb;
#pragma unroll
            for (int j = 0; j < 4; j++) {
                int m = bm + wy * 64 + mt * 16 + kg * 4 + j;
                int f = m >> 10, nn = m & 1023;
                base[((size_t)(h * 16 + f) * 1024 + nn) * 64 + d] = (bf16)(acc[mt][nt][j] * qs);
            }
        }
    }
}

// ---------------- K1c: gather+transpose V -> Vtc [b'][d][c], zero-pad ----------------
__global__ __launch_bounds__(256) void k_vtg(const bf16* __restrict__ V, bf16* __restrict__ Vtc,
                                             const int* __restrict__ idxU, const int* __restrict__ meta) {
    __shared__ bf16 t[64][80];
    int bp = blockIdx.y, c0 = blockIdx.x * 64;
    int nU = meta[0], nUp = meta[1] << 6;
    if (c0 >= nUp) return;
    int tid = threadIdx.x;
    int nl = tid >> 2, dc = (tid & 3) * 16;
    int c = c0 + nl;
    bf16x8 a0 = {}, a1 = {};
    if (c < nU) {
        int row = idxU[c];
        const bf16* src = V + ((size_t)bp * 1024 + row) * 64 + dc;
        a0 = *(const bf16x8*)src;
        a1 = *(const bf16x8*)(src + 8);
    }
    *(bf16x8*)&t[nl][dc] = a0;
    *(bf16x8*)&t[nl][dc + 8] = a1;
    __syncthreads();
    int dl = tid >> 2, nc = (tid & 3) * 16;
    bf16x8 o0, o1;
#pragma unroll
    for (int i = 0; i < 8; i++) o0[i] = t[nc + i][dl];
#pragma unroll
    for (int i = 0; i < 8; i++) o1[i] = t[nc + 8 + i][dl];
    bf16* dst = Vtc + ((size_t)bp * 64 + dl) * 1024 + c0 + nc;
    *(bf16x8*)dst = o0;
    *(bf16x8*)(dst + 8) = o1;
}

// ---------------- K2: flash attention, T14 async-STAGE split (reg-staged K/V) ----------
__global__ __launch_bounds__(512) void k_attn(const bf16* __restrict__ Qb, const bf16* __restrict__ Kb,
                                              const bf16* __restrict__ Vtc, bf16* __restrict__ AO,
                                              const int* __restrict__ cpos, const int* __restrict__ idxU,
                                              const int* __restrict__ meta, const int* __restrict__ diagp) {
    __shared__ char Ks[8192], Vs[8192], Ps[16384];
    int tid = threadIdx.x, l = tid & 63, w = tid >> 6;   // w: 0..7
    int id = blockIdx.x;
    int wg = (id & 7) * 128 + (id >> 3);          // 1024 = 8*128: 16 whole bp's per XCD
    int qt = wg & 7, bp = wg >> 3;                // 8 q-tiles of 128 rows
    int lr = l & 15, kg = l >> 4;
    int diag = diagp[0];
    int nU = meta[0], nT = meta[1];

    int nq = qt * 128 + w * 16 + lr;
    const char* Qrow = (const char*)Qb + ((size_t)bp * 1024 + nq) * 128;
    bf16x8 qf0 = *(const bf16x8*)(Qrow + kg * 16);
    bf16x8 qf1 = *(const bf16x8*)(Qrow + 64 + kg * 16);

    int cq[4];
#pragma unroll
    for (int j = 0; j < 4; j++) {
        int qg = qt * 128 + w * 16 + kg * 4 + j;
        cq[j] = diag ? cpos[qg] : -1;
    }
    int cqmax = cq[0];
#pragma unroll
    for (int j = 1; j < 4; j++) cqmax = (cq[j] > cqmax) ? cq[j] : cqmax;
    int cqmin = cq[0];
#pragma unroll
    for (int j = 1; j < 4; j++) cqmin = (cq[j] < cqmin) ? cq[j] : cqmin;
    int dtile_lo = cqmin >> 6, dtile_hi = cqmax >> 6;

    const char* Kbb = (const char*)Kb + (size_t)bp * 1024 * 128;
    const char* Vbase = (const char*)Vtc + (size_t)bp * 64 * 2048;

    int rs = tid >> 3;                            // staging row 0..63
    int cs = (tid & 7) ^ (rs & 7);                // pre-swizzled source chunk

    f32x4 o[4] = {};
    f32x4 psum = {0.f, 0.f, 0.f, 0.f};

    bf16x8 kreg = *(const bf16x8*)(Kbb + (size_t)idxU[rs] * 128 + cs * 16);
    bf16x8 vreg = *(const bf16x8*)(Vbase + (size_t)rs * 2048 + cs * 16);

    for (int kt = 0; kt < nT; kt++) {
        __syncthreads();   // all reads of tile kt-1 done
        *(bf16x8*)(Ks + tid * 16) = kreg;
        *(bf16x8*)(Vs + tid * 16) = vreg;
        if (kt + 1 < nT) {
            kreg = *(const bf16x8*)(Kbb + (size_t)idxU[(kt + 1) * 64 + rs] * 128 + cs * 16);
            vreg = *(const bf16x8*)(Vbase + (size_t)rs * 2048 + (kt + 1) * 128 + cs * 16);
        }
        __syncthreads();   // ds_writes visible

        f32x4 s[4] = {};
        __builtin_amdgcn_s_setprio(1);
#pragma unroll
        for (int nt = 0; nt < 4; nt++) {
            int r = nt * 16 + lr;
            bf16x8 kf0 = *(const bf16x8*)(Ks + r * 128 + ((kg ^ (r & 7)) << 4));
            bf16x8 kf1 = *(const bf16x8*)(Ks + r * 128 + (((4 + kg) ^ (r & 7)) << 4));
            s[nt] = __builtin_amdgcn_mfma_f32_16x16x32_bf16(qf0, kf0, s[nt], 0, 0, 0);
            s[nt] = __builtin_amdgcn_mfma_f32_16x16x32_bf16(qf1, kf1, s[nt], 0, 0, 0);
        }
        __builtin_amdgcn_s_setprio(0);

#pragma unroll
        for (int nt = 0; nt < 4; nt++)
#pragma unroll
            for (int j = 0; j < 4; j++) s[nt][j] = fast_exp2(s[nt][j]);

        if (kt == nT - 1) {
            float mf0 = (kt * 64 + lr < nU) ? 1.f : 0.f;
            float mf1 = (kt * 64 + 16 + lr < nU) ? 1.f : 0.f;
            float mf2 = (kt * 64 + 32 + lr < nU) ? 1.f : 0.f;
            float mf3 = (kt * 64 + 48 + lr < nU) ? 1.f : 0.f;
#pragma unroll
            for (int j = 0; j < 4; j++) {
                s[0][j] *= mf0; s[1][j] *= mf1; s[2][j] *= mf2; s[3][j] *= mf3;
            }
        }
        if (kt >= dtile_lo && kt <= dtile_hi) {
#pragma unroll
            for (int nt = 0; nt < 4; nt++) {
                int c = kt * 64 + nt * 16 + lr;
#pragma unroll
                for (int j = 0; j < 4; j++)
                    if (c == cq[j]) s[nt][j] = 0.f;
            }
        }
#pragma unroll
        for (int j = 0; j < 4; j++) psum[j] += (s[0][j] + s[1][j]) + (s[2][j] + s[3][j]);

#pragma unroll
        for (int nt = 0; nt < 4; nt++)
#pragma unroll
            for (int j = 0; j < 4; j++) {
                int rq = w * 16 + kg * 4 + j;
                int byte = (rq * 128 + (nt * 16 + lr) * 2) ^ ((rq & 7) << 4);
                *(bf16*)(Ps + byte) = (bf16)s[nt][j];
            }

        int rp = w * 16 + lr;
        bf16x8 pf0 = *(const bf16x8*)(Ps + rp * 128 + ((kg ^ (rp & 7)) << 4));
        bf16x8 pf1 = *(const bf16x8*)(Ps + rp * 128 + (((4 + kg) ^ (rp & 7)) << 4));
        __builtin_amdgcn_s_setprio(1);
#pragma unroll
        for (int dt = 0; dt < 4; dt++) {
            int rd = dt * 16 + lr;
            bf16x8 vf0 = *(const bf16x8*)(Vs + rd * 128 + ((kg ^ (rd & 7)) << 4));
            bf16x8 vf1 = *(const bf16x8*)(Vs + rd * 128 + (((4 + kg) ^ (rd & 7)) << 4));
            o[dt] = __builtin_amdgcn_mfma_f32_16x16x32_bf16(pf0, vf0, o[dt], 0, 0, 0);
            o[dt] = __builtin_amdgcn_mfma_f32_16x16x32_bf16(pf1, vf1, o[dt], 0, 0, 0);
        }
        __builtin_amdgcn_s_setprio(0);
    }

#pragma unroll
    for (int off = 1; off < 16; off <<= 1)
#pragma unroll
        for (int j = 0; j < 4; j++) psum[j] += __shfl_xor(psum[j], off, 64);
    float inv[4];
#pragma unroll
    for (int j = 0; j < 4; j++) inv[j] = 1.0f / psum[j];

    int f = bp & 15, h = bp >> 4;
#pragma unroll
    for (int dt = 0; dt < 4; dt++)
#pragma unroll
        for (int j = 0; j < 4; j++) {
            int n = qt * 128 + w * 16 + kg * 4 + j;
            size_t m = (size_t)f * 1024 + n;
            AO[m * 512 + h * 64 + dt * 16 + lr] = (bf16)(o[dt][j] * inv[j]);
        }
}

// ---------------- K3: out = AO @ WoutT^T (fp32 out), BK=32 double-buffered ----------------
__global__ __launch_bounds__(256) void k_out(const bf16* __restrict__ Ab, const bf16* __restrict__ WT,
                                             float* __restrict__ out) {
    __shared__ char As[2][8192], Bs[2][8192];
    int tid = threadIdx.x, l = tid & 63, w = tid >> 6;
    int wy = w >> 1, wx = w & 1;
    int id = blockIdx.x;
    int wg = (id & 7) * 64 + (id >> 3);           // 512 = 8*64
    int bm = (wg / 4) * 128, bn = (wg % 4) * 128;
    int lr = l & 15, kg = l >> 4;

    int subr = l >> 2, chk = l & 3;
    int R0 = w * 32 + subr,      m0 = (R0 >> 1) & 3, c0 = chk ^ m0;
    int R1 = w * 32 + 16 + subr, m1 = (R1 >> 1) & 3, c1 = chk ^ m1;

    f32x4 acc[4][4] = {};

    gload_lds16((const char*)Ab + ((size_t)(bm + R0) * 512) * 2 + c0 * 16, As[0] + w * 2048 + l * 16);
    gload_lds16((const char*)Ab + ((size_t)(bm + R1) * 512) * 2 + c1 * 16, As[0] + w * 2048 + 1024 + l * 16);
    gload_lds16((const char*)WT + ((size_t)(bn + R0) * 512) * 2 + c0 * 16, Bs[0] + w * 2048 + l * 16);
    gload_lds16((const char*)WT + ((size_t)(bn + R1) * 512) * 2 + c1 * 16, Bs[0] + w * 2048 + 1024 + l * 16);
    __syncthreads();

    for (int t = 0; t < 16; t++) {
        int cur = t & 1;
        if (t < 15) {
            int k1 = (t + 1) * 32;
            gload_lds16((const char*)Ab + ((size_t)(bm + R0) * 512 + k1) * 2 + c0 * 16, As[cur ^ 1] + w * 2048 + l * 16);
            gload_lds16((const char*)Ab + ((size_t)(bm + R1) * 512 + k1) * 2 + c1 * 16, As[cur ^ 1] + w * 2048 + 1024 + l * 16);
            gload_lds16((const char*)WT + ((size_t)(bn + R0) * 512 + k1) * 2 + c0 * 16, Bs[cur ^ 1] + w * 2048 + l * 16);
            gload_lds16((const char*)WT + ((size_t)(bn + R1) * 512 + k1) * 2 + c1 * 16, Bs[cur ^ 1] + w * 2048 + 1024 + l * 16);
        }

        bf16x8 af[4], bfr[4];
#pragma unroll
        for (int mt = 0; mt < 4; mt++) {
            int r = wy * 64 + mt * 16 + lr;
            af[mt] = *(const bf16x8*)(As[cur] + r * 64 + ((kg ^ ((r >> 1) & 3)) << 4));
        }
#pragma unroll
        for (int nt = 0; nt < 4; nt++) {
            int r = wx * 64 + nt * 16 + lr;
            bfr[nt] = *(const bf16x8*)(Bs[cur] + r * 64 + ((kg ^ ((r >> 1) & 3)) << 4));
        }
#pragma unroll
        for (int mt = 0; mt < 4; mt++)
#pragma unroll
            for (int nt = 0; nt < 4; nt++)
                acc[mt][nt] = __builtin_amdgcn_mfma_f32_16x16x32_bf16(af[mt], bfr[nt], acc[mt][nt], 0, 0, 0);

        __syncthreads();
    }

#pragma unroll
    for (int mt = 0; mt < 4; mt++)
#pragma unroll
        for (int nt = 0; nt < 4; nt++) {
            int c = bn + wx * 64 + nt * 16 + lr;
#pragma unroll
            for (int j = 0; j < 4; j++) {
                int m = bm + wy * 64 + mt * 16 + kg * 4 + j;
                out[(size_t)m * 512 + c] = acc[mt][nt][j];
            }
        }
}

extern "C" void kernel_launch(void* const* d_in, const int* in_sizes, int n_in,
                              void* d_out, int out_size, void* d_ws, size_t ws_size,
                              hipStream_t stream) {
    const float* x    = (const float*)d_in[0];
    const float* Wqkv = (const float*)d_in[1];
    const float* Wout = (const float*)d_in[2];
    const int*   mask = (const int*)d_in[3];
    const int*   diag = (const int*)d_in[4];
    float* out = (float*)d_out;
    char* ws = (char*)d_ws;

    bf16* Xb  = (bf16*)(ws);                             // 16 MB, dead after k_qkv
    bf16* Vtc = (bf16*)(ws);                             // V^T compacted, reuses Xb
    bf16* WqT = (bf16*)(ws + ((size_t)16 << 20));        // 1.5 MB
    bf16* WoT = (bf16*)(ws + ((size_t)18 << 20));        // 0.5 MB
    int*  idxU = (int*)(ws + ((size_t)18 << 20) + (1 << 19));            // 4 KB
    int*  cpos = (int*)(ws + ((size_t)18 << 20) + (1 << 19) + 4096);     // 4 KB
    int*  meta = (int*)(ws + ((size_t)18 << 20) + (1 << 19) + 8192);     // 8 B
    bf16* Qb  = (bf16*)(ws + ((size_t)19 << 20));        // 16 MB
    bf16* Kb  = (bf16*)(ws + ((size_t)35 << 20));        // 16 MB (row-major K, live through k_attn)
    bf16* Vb  = (bf16*)(ws + ((size_t)51 << 20));        // 16 MB, dead after k_vtg
    bf16* AO  = (bf16*)(ws + ((size_t)67 << 20));        // 16 MB

    hipLaunchKernelGGL(k_prep, dim3(4096 + 768 + 256 + 1), dim3(256), 0, stream,
                       x, Xb, Wqkv, WqT, Wout, WoT, mask, idxU, cpos, meta);
    hipLaunchKernelGGL(k_qkv, dim3(1536), dim3(256), 0, stream, Xb, WqT, Qb, Kb, Vb);
    hipLaunchKernelGGL(k_vtg, dim3(16, 128), dim3(256), 0, stream, Vb, Vtc, idxU, meta);
    hipLaunchKernelGGL(k_attn, dim3(1024), dim3(512), 0, stream, Qb, Kb, Vtc, AO, cpos, idxU, meta, diag);
    hipLaunchKernelGGL(k_out, dim3(512), dim3(256), 0, stream, AO, WoT, out);
}

// Round 23
// 108.755 us; speedup vs baseline: 1.3486x; 1.0001x over previous
//
#include <hip/hip_runtime.h>
#include <stdint.h>

typedef __bf16 bf16;
typedef __bf16 bf16x8 __attribute__((ext_vector_type(8)));
typedef float f32x4 __attribute__((ext_vector_type(4)));

__device__ __forceinline__ void gload_lds16(const void* g, void* l) {
    __builtin_amdgcn_global_load_lds((const __attribute__((address_space(1))) void*)g,
                                     (__attribute__((address_space(3))) void*)l, 16, 0, 0);
}

__device__ __forceinline__ float fast_exp2(float x) { return __builtin_amdgcn_exp2f(x); }

// ---------------- K0: fused prep: cast x, transpose weights, mask scan ----------------
__global__ __launch_bounds__(256) void k_prep(const float* __restrict__ x, bf16* __restrict__ xb,
                                              const float* __restrict__ Wqkv, bf16* __restrict__ WqT,
                                              const float* __restrict__ Wout, bf16* __restrict__ WoT,
                                              const int* __restrict__ mask, int* __restrict__ idxU,
                                              int* __restrict__ cpos, int* __restrict__ meta) {
    __shared__ float t[32][33];
    __shared__ int lsum[256];
    int b = blockIdx.x, tid = threadIdx.x;
    if (b < 4096) {
        int i = b * 256 + tid;
        const f32x4* p = (const f32x4*)(x + (size_t)i * 8);
        f32x4 a = p[0], c = p[1];
        bf16x8 o;
        o[0] = (bf16)a[0]; o[1] = (bf16)a[1]; o[2] = (bf16)a[2]; o[3] = (bf16)a[3];
        o[4] = (bf16)c[0]; o[5] = (bf16)c[1]; o[6] = (bf16)c[2]; o[7] = (bf16)c[3];
        *(bf16x8*)(xb + (size_t)i * 8) = o;
    } else if (b < 4096 + 768 + 256) {
        const float* W; bf16* WT; int C, bb;
        if (b < 4096 + 768) { W = Wqkv; WT = WqT; C = 1536; bb = b - 4096; }
        else                { W = Wout; WT = WoT; C = 512;  bb = b - 4864; }
        int nblk = C / 32;
        int n0 = (bb % nblk) * 32, k0 = (bb / nblk) * 32;
        int tx = tid & 31, ty = tid >> 5;
        for (int i = 0; i < 32; i += 8) t[ty + i][tx] = W[(size_t)(k0 + ty + i) * C + n0 + tx];
        __syncthreads();
        for (int i = 0; i < 32; i += 8) WT[(size_t)(n0 + ty + i) * 512 + k0 + tx] = (bf16)t[tx][ty + i];
    } else {
        int m[4], s = 0;
#pragma unroll
        for (int e = 0; e < 4; e++) { m[e] = mask[4 * tid + e]; s += m[e]; }
        lsum[tid] = s;
        __syncthreads();
        for (int off = 1; off < 256; off <<= 1) {
            int v = (tid >= off) ? lsum[tid - off] : 0;
            __syncthreads();
            lsum[tid] += v;
            __syncthreads();
        }
        int run = lsum[tid] - s;
#pragma unroll
        for (int e = 0; e < 4; e++) {
            if (m[e]) { idxU[run] = 4 * tid + e; cpos[4 * tid + e] = run; run++; }
            else cpos[4 * tid + e] = -1;
        }
        int nU = lsum[255];
        for (int i = nU + tid; i < 1024; i += 256) idxU[i] = 0;   // pad rows -> row 0 (masked later)
        if (tid == 255) { meta[0] = nU; meta[1] = (nU + 63) >> 6; }
    }
}

// ---------------- K1: qkv GEMM 128x128, 3-buffer 2-deep prefetch, counted vmcnt(4) ----------
// Per step: [vmcnt(4); s_barrier] -> compute(t) -> stage(t+2). Tile t+1's loads stay in
// flight across the barrier (T4); only tile t's (oldest, in-order) are drained.
__global__ __launch_bounds__(256) void k_qkv(const bf16* __restrict__ Xb, const bf16* __restrict__ WT,
                                             bf16* __restrict__ Qb, bf16* __restrict__ Kb, bf16* __restrict__ Vb) {
    __shared__ char As[3][8192], Bs[3][8192];
    int tid = threadIdx.x, l = tid & 63, w = tid >> 6;
    int wy = w >> 1, wx = w & 1;
    int id = blockIdx.x;
    int wg = (id & 7) * 192 + (id >> 3);          // 1536 = 8*192, bijective XCD chunking
    int bm = (wg / 12) * 128, bn = (wg % 12) * 128;
    int lr = l & 15, kg = l >> 4;

    int subr = l >> 2, chk = l & 3;
    int R0 = w * 32 + subr,      c0 = chk ^ ((R0 >> 1) & 3);
    int R1 = w * 32 + 16 + subr, c1 = chk ^ ((R1 >> 1) & 3);

    const char* xA0 = (const char*)Xb + ((size_t)(bm + R0) * 512) * 2 + c0 * 16;
    const char* xA1 = (const char*)Xb + ((size_t)(bm + R1) * 512) * 2 + c1 * 16;
    const char* wB0 = (const char*)WT + ((size_t)(bn + R0) * 512) * 2 + c0 * 16;
    const char* wB1 = (const char*)WT + ((size_t)(bn + R1) * 512) * 2 + c1 * 16;

    f32x4 acc[4][4] = {};

#define QKV_STAGE(T, BUF)                                                   \
    do {                                                                    \
        int k0b = (T) * 64;                                                 \
        gload_lds16(xA0 + k0b, As[BUF] + w * 2048 + l * 16);                \
        gload_lds16(xA1 + k0b, As[BUF] + w * 2048 + 1024 + l * 16);         \
        gload_lds16(wB0 + k0b, Bs[BUF] + w * 2048 + l * 16);                \
        gload_lds16(wB1 + k0b, Bs[BUF] + w * 2048 + 1024 + l * 16);         \
    } while (0)

    QKV_STAGE(0, 0);
    QKV_STAGE(1, 1);

#define QKV_COMPUTE(CUR)                                                    \
    do {                                                                    \
        bf16x8 af[4], bfr[4];                                               \
        _Pragma("unroll")                                                   \
        for (int mt = 0; mt < 4; mt++) {                                    \
            int r = wy * 64 + mt * 16 + lr;                                 \
            af[mt] = *(const bf16x8*)(As[CUR] + r * 64 + ((kg ^ ((r >> 1) & 3)) << 4)); \
        }                                                                   \
        _Pragma("unroll")                                                   \
        for (int nt = 0; nt < 4; nt++) {                                    \
            int r = wx * 64 + nt * 16 + lr;                                 \
            bfr[nt] = *(const bf16x8*)(Bs[CUR] + r * 64 + ((kg ^ ((r >> 1) & 3)) << 4)); \
        }                                                                   \
        _Pragma("unroll")                                                   \
        for (int mt = 0; mt < 4; mt++)                                      \
            _Pragma("unroll")                                               \
            for (int nt = 0; nt < 4; nt++)                                  \
                acc[mt][nt] = __builtin_amdgcn_mfma_f32_16x16x32_bf16(af[mt], bfr[nt], acc[mt][nt], 0, 0, 0); \
    } while (0)

    for (int t = 0; t < 15; t++) {
        asm volatile("s_waitcnt vmcnt(4)" ::: "memory");   // tile t's loads done; t+1's may fly
        __builtin_amdgcn_s_barrier();
        __builtin_amdgcn_sched_barrier(0);
        int cur = t % 3;
        QKV_COMPUTE(cur);
        if (t + 2 < 16) QKV_STAGE(t + 2, (t + 2) % 3);
        __builtin_amdgcn_sched_barrier(0);
    }
    asm volatile("s_waitcnt vmcnt(0)" ::: "memory");       // tail: tile 15 has no younger loads
    __builtin_amdgcn_s_barrier();
    __builtin_amdgcn_sched_barrier(0);
    QKV_COMPUTE(15 % 3);
#undef QKV_STAGE
#undef QKV_COMPUTE

#pragma unroll
    for (int mt = 0; mt < 4; mt++) {
#pragma unroll
        for (int nt = 0; nt < 4; nt++) {
            int c = bn + wx * 64 + nt * 16 + lr;
            int which = c >> 9, hd = c & 511, h = hd >> 6, d = hd & 63;
            float qs = (which == 0) ? 0.18033688f : 1.0f;   // 0.125 * log2(e)
            bf16* base = (which == 0) ? Qb : (which == 1) ? Kb : Vb;
#pragma unroll
            for (int j = 0; j < 4; j++) {
                int m = bm + wy * 64 + mt * 16 + kg * 4 + j;
                int f = m >> 10, nn = m & 1023;
                base[((size_t)(h * 16 + f) * 1024 + nn) * 64 + d] = (bf16)(acc[mt][nt][j] * qs);
            }
        }
    }
}

// ---------------- K1c: gather+transpose V -> Vtc [b'][d][c], zero-pad ----------------
__global__ __launch_bounds__(256) void k_vtg(const bf16* __restrict__ V, bf16* __restrict__ Vtc,
                                             const int* __restrict__ idxU, const int* __restrict__ meta) {
    __shared__ bf16 t[64][80];
    int bp = blockIdx.y, c0 = blockIdx.x * 64;
    int nU = meta[0], nUp = meta[1] << 6;
    if (c0 >= nUp) return;
    int tid = threadIdx.x;
    int nl = tid >> 2, dc = (tid & 3) * 16;
    int c = c0 + nl;
    bf16x8 a0 = {}, a1 = {};
    if (c < nU) {
        int row = idxU[c];
        const bf16* src = V + ((size_t)bp * 1024 + row) * 64 + dc;
        a0 = *(const bf16x8*)src;
        a1 = *(const bf16x8*)(src + 8);
    }
    *(bf16x8*)&t[nl][dc] = a0;
    *(bf16x8*)&t[nl][dc + 8] = a1;
    __syncthreads();
    int dl = tid >> 2, nc = (tid & 3) * 16;
    bf16x8 o0, o1;
#pragma unroll
    for (int i = 0; i < 8; i++) o0[i] = t[nc + i][dl];
#pragma unroll
    for (int i = 0; i < 8; i++) o1[i] = t[nc + 8 + i][dl];
    bf16* dst = Vtc + ((size_t)bp * 64 + dl) * 1024 + c0 + nc;
    *(bf16x8*)dst = o0;
    *(bf16x8*)(dst + 8) = o1;
}

// ---------------- K2: flash attention, T14 async-STAGE split (reg-staged K/V) ----------
__global__ __launch_bounds__(512) void k_attn(const bf16* __restrict__ Qb, const bf16* __restrict__ Kb,
                                              const bf16* __restrict__ Vtc, bf16* __restrict__ AO,
                                              const int* __restrict__ cpos, const int* __restrict__ idxU,
                                              const int* __restrict__ meta, const int* __restrict__ diagp) {
    __shared__ char Ks[8192], Vs[8192], Ps[16384];
    int tid = threadIdx.x, l = tid & 63, w = tid >> 6;   // w: 0..7
    int id = blockIdx.x;
    int wg = (id & 7) * 128 + (id >> 3);          // 1024 = 8*128: 16 whole bp's per XCD
    int qt = wg & 7, bp = wg >> 3;                // 8 q-tiles of 128 rows
    int lr = l & 15, kg = l >> 4;
    int diag = diagp[0];
    int nU = meta[0], nT = meta[1];

    int nq = qt * 128 + w * 16 + lr;
    const char* Qrow = (const char*)Qb + ((size_t)bp * 1024 + nq) * 128;
    bf16x8 qf0 = *(const bf16x8*)(Qrow + kg * 16);
    bf16x8 qf1 = *(const bf16x8*)(Qrow + 64 + kg * 16);

    int cq[4];
#pragma unroll
    for (int j = 0; j < 4; j++) {
        int qg = qt * 128 + w * 16 + kg * 4 + j;
        cq[j] = diag ? cpos[qg] : -1;
    }
    int cqmax = cq[0];
#pragma unroll
    for (int j = 1; j < 4; j++) cqmax = (cq[j] > cqmax) ? cq[j] : cqmax;
    int cqmin = cq[0];
#pragma unroll
    for (int j = 1; j < 4; j++) cqmin = (cq[j] < cqmin) ? cq[j] : cqmin;
    int dtile_lo = cqmin >> 6, dtile_hi = cqmax >> 6;

    const char* Kbb = (const char*)Kb + (size_t)bp * 1024 * 128;
    const char* Vbase = (const char*)Vtc + (size_t)bp * 64 * 2048;

    int rs = tid >> 3;                            // staging row 0..63
    int cs = (tid & 7) ^ (rs & 7);                // pre-swizzled source chunk

    f32x4 o[4] = {};
    f32x4 psum = {0.f, 0.f, 0.f, 0.f};

    bf16x8 kreg = *(const bf16x8*)(Kbb + (size_t)idxU[rs] * 128 + cs * 16);
    bf16x8 vreg = *(const bf16x8*)(Vbase + (size_t)rs * 2048 + cs * 16);

    for (int kt = 0; kt < nT; kt++) {
        __syncthreads();   // all reads of tile kt-1 done
        *(bf16x8*)(Ks + tid * 16) = kreg;
        *(bf16x8*)(Vs + tid * 16) = vreg;
        if (kt + 1 < nT) {
            kreg = *(const bf16x8*)(Kbb + (size_t)idxU[(kt + 1) * 64 + rs] * 128 + cs * 16);
            vreg = *(const bf16x8*)(Vbase + (size_t)rs * 2048 + (kt + 1) * 128 + cs * 16);
        }
        __syncthreads();   // ds_writes visible

        f32x4 s[4] = {};
        __builtin_amdgcn_s_setprio(1);
#pragma unroll
        for (int nt = 0; nt < 4; nt++) {
            int r = nt * 16 + lr;
            bf16x8 kf0 = *(const bf16x8*)(Ks + r * 128 + ((kg ^ (r & 7)) << 4));
            bf16x8 kf1 = *(const bf16x8*)(Ks + r * 128 + (((4 + kg) ^ (r & 7)) << 4));
            s[nt] = __builtin_amdgcn_mfma_f32_16x16x32_bf16(qf0, kf0, s[nt], 0, 0, 0);
            s[nt] = __builtin_amdgcn_mfma_f32_16x16x32_bf16(qf1, kf1, s[nt], 0, 0, 0);
        }
        __builtin_amdgcn_s_setprio(0);

#pragma unroll
        for (int nt = 0; nt < 4; nt++)
#pragma unroll
            for (int j = 0; j < 4; j++) s[nt][j] = fast_exp2(s[nt][j]);

        if (kt == nT - 1) {
            float mf0 = (kt * 64 + lr < nU) ? 1.f : 0.f;
            float mf1 = (kt * 64 + 16 + lr < nU) ? 1.f : 0.f;
            float mf2 = (kt * 64 + 32 + lr < nU) ? 1.f : 0.f;
            float mf3 = (kt * 64 + 48 + lr < nU) ? 1.f : 0.f;
#pragma unroll
            for (int j = 0; j < 4; j++) {
                s[0][j] *= mf0; s[1][j] *= mf1; s[2][j] *= mf2; s[3][j] *= mf3;
            }
        }
        if (kt >= dtile_lo && kt <= dtile_hi) {
#pragma unroll
            for (int nt = 0; nt < 4; nt++) {
                int c = kt * 64 + nt * 16 + lr;
#pragma unroll
                for (int j = 0; j < 4; j++)
                    if (c == cq[j]) s[nt][j] = 0.f;
            }
        }
#pragma unroll
        for (int j = 0; j < 4; j++) psum[j] += (s[0][j] + s[1][j]) + (s[2][j] + s[3][j]);

#pragma unroll
        for (int nt = 0; nt < 4; nt++)
#pragma unroll
            for (int j = 0; j < 4; j++) {
                int rq = w * 16 + kg * 4 + j;
                int byte = (rq * 128 + (nt * 16 + lr) * 2) ^ ((rq & 7) << 4);
                *(bf16*)(Ps + byte) = (bf16)s[nt][j];
            }

        int rp = w * 16 + lr;
        bf16x8 pf0 = *(const bf16x8*)(Ps + rp * 128 + ((kg ^ (rp & 7)) << 4));
        bf16x8 pf1 = *(const bf16x8*)(Ps + rp * 128 + (((4 + kg) ^ (rp & 7)) << 4));
        __builtin_amdgcn_s_setprio(1);
#pragma unroll
        for (int dt = 0; dt < 4; dt++) {
            int rd = dt * 16 + lr;
            bf16x8 vf0 = *(const bf16x8*)(Vs + rd * 128 + ((kg ^ (rd & 7)) << 4));
            bf16x8 vf1 = *(const bf16x8*)(Vs + rd * 128 + (((4 + kg) ^ (rd & 7)) << 4));
            o[dt] = __builtin_amdgcn_mfma_f32_16x16x32_bf16(pf0, vf0, o[dt], 0, 0, 0);
            o[dt] = __builtin_amdgcn_mfma_f32_16x16x32_bf16(pf1, vf1, o[dt], 0, 0, 0);
        }
        __builtin_amdgcn_s_setprio(0);
    }

#pragma unroll
    for (int off = 1; off < 16; off <<= 1)
#pragma unroll
        for (int j = 0; j < 4; j++) psum[j] += __shfl_xor(psum[j], off, 64);
    float inv[4];
#pragma unroll
    for (int j = 0; j < 4; j++) inv[j] = 1.0f / psum[j];

    int f = bp & 15, h = bp >> 4;
#pragma unroll
    for (int dt = 0; dt < 4; dt++)
#pragma unroll
        for (int j = 0; j < 4; j++) {
            int n = qt * 128 + w * 16 + kg * 4 + j;
            size_t m = (size_t)f * 1024 + n;
            AO[m * 512 + h * 64 + dt * 16 + lr] = (bf16)(o[dt][j] * inv[j]);
        }
}

// ---------------- K3: out = AO @ WoutT^T (fp32), 3-buffer 2-deep prefetch, vmcnt(4) ----------
__global__ __launch_bounds__(256) void k_out(const bf16* __restrict__ Ab, const bf16* __restrict__ WT,
                                             float* __restrict__ out) {
    __shared__ char As[3][8192], Bs[3][8192];
    int tid = threadIdx.x, l = tid & 63, w = tid >> 6;
    int wy = w >> 1, wx = w & 1;
    int id = blockIdx.x;
    int wg = (id & 7) * 64 + (id >> 3);           // 512 = 8*64
    int bm = (wg / 4) * 128, bn = (wg % 4) * 128;
    int lr = l & 15, kg = l >> 4;

    int subr = l >> 2, chk = l & 3;
    int R0 = w * 32 + subr,      c0 = chk ^ ((R0 >> 1) & 3);
    int R1 = w * 32 + 16 + subr, c1 = chk ^ ((R1 >> 1) & 3);

    const char* aA0 = (const char*)Ab + ((size_t)(bm + R0) * 512) * 2 + c0 * 16;
    const char* aA1 = (const char*)Ab + ((size_t)(bm + R1) * 512) * 2 + c1 * 16;
    const char* wB0 = (const char*)WT + ((size_t)(bn + R0) * 512) * 2 + c0 * 16;
    const char* wB1 = (const char*)WT + ((size_t)(bn + R1) * 512) * 2 + c1 * 16;

    f32x4 acc[4][4] = {};

#define OUT_STAGE(T, BUF)                                                   \
    do {                                                                    \
        int k0b = (T) * 64;                                                 \
        gload_lds16(aA0 + k0b, As[BUF] + w * 2048 + l * 16);                \
        gload_lds16(aA1 + k0b, As[BUF] + w * 2048 + 1024 + l * 16);         \
        gload_lds16(wB0 + k0b, Bs[BUF] + w * 2048 + l * 16);                \
        gload_lds16(wB1 + k0b, Bs[BUF] + w * 2048 + 1024 + l * 16);         \
    } while (0)

    OUT_STAGE(0, 0);
    OUT_STAGE(1, 1);

#define OUT_COMPUTE(CUR)                                                    \
    do {                                                                    \
        bf16x8 af[4], bfr[4];                                               \
        _Pragma("unroll")                                                   \
        for (int mt = 0; mt < 4; mt++) {                                    \
            int r = wy * 64 + mt * 16 + lr;                                 \
            af[mt] = *(const bf16x8*)(As[CUR] + r * 64 + ((kg ^ ((r >> 1) & 3)) << 4)); \
        }                                                                   \
        _Pragma("unroll")                                                   \
        for (int nt = 0; nt < 4; nt++) {                                    \
            int r = wx * 64 + nt * 16 + lr;                                 \
            bfr[nt] = *(const bf16x8*)(Bs[CUR] + r * 64 + ((kg ^ ((r >> 1) & 3)) << 4)); \
        }                                                                   \
        _Pragma("unroll")                                                   \
        for (int mt = 0; mt < 4; mt++)                                      \
            _Pragma("unroll")                                               \
            for (int nt = 0; nt < 4; nt++)                                  \
                acc[mt][nt] = __builtin_amdgcn_mfma_f32_16x16x32_bf16(af[mt], bfr[nt], acc[mt][nt], 0, 0, 0); \
    } while (0)

    for (int t = 0; t < 15; t++) {
        asm volatile("s_waitcnt vmcnt(4)" ::: "memory");
        __builtin_amdgcn_s_barrier();
        __builtin_amdgcn_sched_barrier(0);
        int cur = t % 3;
        OUT_COMPUTE(cur);
        if (t + 2 < 16) OUT_STAGE(t + 2, (t + 2) % 3);
        __builtin_amdgcn_sched_barrier(0);
    }
    asm volatile("s_waitcnt vmcnt(0)" ::: "memory");
    __builtin_amdgcn_s_barrier();
    __builtin_amdgcn_sched_barrier(0);
    OUT_COMPUTE(15 % 3);
#undef OUT_STAGE
#undef OUT_COMPUTE

#pragma unroll
    for (int mt = 0; mt < 4; mt++)
#pragma unroll
        for (int nt = 0; nt < 4; nt++) {
            int c = bn + wx * 64 + nt * 16 + lr;
#pragma unroll
            for (int j = 0; j < 4; j++) {
                int m = bm + wy * 64 + mt * 16 + kg * 4 + j;
                out[(size_t)m * 512 + c] = acc[mt][nt][j];
            }
        }
}

extern "C" void kernel_launch(void* const* d_in, const int* in_sizes, int n_in,
                              void* d_out, int out_size, void* d_ws, size_t ws_size,
                              hipStream_t stream) {
    const float* x    = (const float*)d_in[0];
    const float* Wqkv = (const float*)d_in[1];
    const float* Wout = (const float*)d_in[2];
    const int*   mask = (const int*)d_in[3];
    const int*   diag = (const int*)d_in[4];
    float* out = (float*)d_out;
    char* ws = (char*)d_ws;

    bf16* Xb  = (bf16*)(ws);                             // 16 MB, dead after k_qkv
    bf16* Vtc = (bf16*)(ws);                             // V^T compacted, reuses Xb
    bf16* WqT = (bf16*)(ws + ((size_t)16 << 20));        // 1.5 MB
    bf16* WoT = (bf16*)(ws + ((size_t)18 << 20));        // 0.5 MB
    int*  idxU = (int*)(ws + ((size_t)18 << 20) + (1 << 19));            // 4 KB
    int*  cpos = (int*)(ws + ((size_t)18 << 20) + (1 << 19) + 4096);     // 4 KB
    int*  meta = (int*)(ws + ((size_t)18 << 20) + (1 << 19) + 8192);     // 8 B
    bf16* Qb  = (bf16*)(ws + ((size_t)19 << 20));        // 16 MB
    bf16* Kb  = (bf16*)(ws + ((size_t)35 << 20));        // 16 MB (row-major K, live through k_attn)
    bf16* Vb  = (bf16*)(ws + ((size_t)51 << 20));        // 16 MB, dead after k_vtg
    bf16* AO  = (bf16*)(ws + ((size_t)67 << 20));        // 16 MB

    hipLaunchKernelGGL(k_prep, dim3(4096 + 768 + 256 + 1), dim3(256), 0, stream,
                       x, Xb, Wqkv, WqT, Wout, WoT, mask, idxU, cpos, meta);
    hipLaunchKernelGGL(k_qkv, dim3(1536), dim3(256), 0, stream, Xb, WqT, Qb, Kb, Vb);
    hipLaunchKernelGGL(k_vtg, dim3(16, 128), dim3(256), 0, stream, Vb, Vtc, idxU, meta);
    hipLaunchKernelGGL(k_attn, dim3(1024), dim3(512), 0, stream, Qb, Kb, Vtc, AO, cpos, idxU, meta, diag);
    hipLaunchKernelGGL(k_out, dim3(512), dim3(256), 0, stream, AO, WoT, out);
}